// Round 1
// 166.500 us; speedup vs baseline: 1.0152x; 1.0152x over previous
//
#include <hip/hip_runtime.h>

// Problem: B=2, S=2048, D=1024, H=16, HD=64. fp32 in/out.
// Pipeline exploits head-summed K/V: k_sum = x @ (sum_h Wk_h)^T + sum_h bk_h.
//  1. prep_all:    x, Wout -> f16; wcomb = [Wq; Wred] f16 (1152x1024); bcomb
//  2. gemm_t2<0>:  [Q*scale | k_sum | v_sum^T] = x @ wcomb^T + bcomb (N=1152)
//  3. flash_attn8: 8-wave blocks, wave-pair t-split (g=w>>2 owns sub-tile g),
//                  24 waves/CU (LDS 50K -> 3 blk/CU), defer-rescale, setprio
//  4. gemm_t2<1>:  out = ao @ Wout^T + bout   (4096x1024x1024) -> f32

#define S_LEN 2048
#define DIM 1024

using floatx4 = __attribute__((ext_vector_type(4))) float;
using halfx8  = __attribute__((ext_vector_type(8))) _Float16;
using halfx4  = __attribute__((ext_vector_type(4))) _Float16;

__device__ __forceinline__ floatx4 mfma16(halfx8 a, halfx8 b, floatx4 c) {
  return __builtin_amdgcn_mfma_f32_16x16x32_f16(a, b, c, 0, 0, 0);
}

// async global->LDS, 16B per lane; lds dst is wave-uniform base + lane*16
__device__ __forceinline__ void gll16(const void* g, void* l) {
  __builtin_amdgcn_global_load_lds(
      (const __attribute__((address_space(1))) void*)g,
      (__attribute__((address_space(3))) void*)l, 16, 0, 0);
}

// ---------------- prep: conversions + combined weights ----------------
__global__ __launch_bounds__(256) void prep_all(
    const float* __restrict__ x, const float* __restrict__ wqkv,
    const float* __restrict__ bqkv, const float* __restrict__ wout,
    _Float16* __restrict__ xb, _Float16* __restrict__ wcomb,
    _Float16* __restrict__ woutb, float* __restrict__ bcomb) {
  int bx = blockIdx.x;
  if (bx < 6144) {
    size_t i4 = ((size_t)bx * 256 + threadIdx.x) * 4;
    const float* src;
    _Float16* dst;
    size_t off;
    if (i4 < 4194304) { src = x; dst = xb; off = i4; }
    else if (i4 < 5242880) { src = wqkv; dst = wcomb; off = i4 - 4194304; }
    else { src = wout; dst = woutb; off = i4 - 5242880; }
    float4 v = *(const float4*)(src + off);
    halfx4 o;
    o[0] = (_Float16)v.x; o[1] = (_Float16)v.y;
    o[2] = (_Float16)v.z; o[3] = (_Float16)v.w;
    *(halfx4*)(dst + off) = o;
  } else {
    int gid = (bx - 6144) * 256 + threadIdx.x;  // 131072 threads
    int c = gid >> 10, j = gid & 1023;
    int row0 = (c < 64) ? (1024 + c) : (2048 + c - 64);
    float s = 0.f;
#pragma unroll
    for (int h = 0; h < 16; ++h) s += wqkv[(size_t)(row0 + h * 64) * 1024 + j];
    wcomb[(size_t)1024 * 1024 + gid] = (_Float16)s;
    if (gid < 1024) bcomb[gid] = bqkv[gid];
    if (gid < 128) {
      int b0 = (gid < 64) ? (1024 + gid) : (2048 + gid - 64);
      float sb = 0.f;
#pragma unroll
      for (int h = 0; h < 16; ++h) sb += bqkv[b0 + h * 64];
      bcomb[1024 + gid] = sb;
    }
  }
}

// ------- gemm_t2: 128M x 128N tile (m97-style), BK=64, 2 barriers/step -----
// Wave w -> 64x64 quadrant: rows (w&1)*64, cols (w>>1)*64; 4x4 16x16 frags.
// gll16 staging with XOR col-group swizzle (row r group g at g^(r&7)).
// MODE 0: N=1152 fused epilogue -> qb (*scale), kb, vtb(V^T). MODE 1: f32 out.
template <int MODE>
__global__ __launch_bounds__(256, 2) void gemm_t2(
    const _Float16* __restrict__ A, const _Float16* __restrict__ W,
    const float* __restrict__ bias, void* __restrict__ Cv,
    _Float16* __restrict__ kbo, _Float16* __restrict__ vto) {
  const int K = 1024;
  __shared__ _Float16 As[128][64];  // 16 KB
  __shared__ _Float16 Ws[128][64];  // 16 KB
  int tid = threadIdx.x;
  int lane = tid & 63, w = tid >> 6, ln = lane & 15, q4 = lane >> 4;
  int m0 = blockIdx.x * 128, n0 = blockIdx.y * 128;
  int mh = (w & 1) * 64, nh = (w >> 1) * 64;
  int rr = lane >> 3, gg = ((lane & 7) ^ rr) * 8;  // staging lane row/col
  const _Float16* agp = A + (size_t)(m0 + w * 32 + rr) * K + gg;
  const _Float16* wgp = W + (size_t)(n0 + w * 32 + rr) * K + gg;
  floatx4 acc[4][4] = {};
  for (int kt = 0; kt < K; kt += 64) {
    __syncthreads();  // readers done with previous tile
#pragma unroll
    for (int j = 0; j < 4; ++j) {
      gll16(agp + (size_t)(8 * j) * K + kt, &As[w * 32 + 8 * j][0]);
      gll16(wgp + (size_t)(8 * j) * K + kt, &Ws[w * 32 + 8 * j][0]);
    }
    __syncthreads();  // staging visible
#pragma unroll
    for (int kh = 0; kh < 2; ++kh) {
      int sw = ((q4 + 4 * kh) ^ (ln & 7)) * 8;
      halfx8 bf[4];
#pragma unroll
      for (int nf = 0; nf < 4; ++nf)
        bf[nf] = *(const halfx8*)&Ws[nh + nf * 16 + ln][sw];
#pragma unroll
      for (int mf = 0; mf < 4; ++mf) {
        halfx8 af = *(const halfx8*)&As[mh + mf * 16 + ln][sw];
#pragma unroll
        for (int nf = 0; nf < 4; ++nf)
          acc[mf][nf] = mfma16(af, bf[nf], acc[mf][nf]);
      }
    }
  }
  const float qscale = 0.18033688011112042f;  // (1/sqrt(64)) * log2(e)
#pragma unroll
  for (int nf = 0; nf < 4; ++nf) {
    int col = n0 + nh + nf * 16 + ln;
    float bv = bias[col];
    if constexpr (MODE == 1) {
#pragma unroll
      for (int mf = 0; mf < 4; ++mf)
#pragma unroll
        for (int i = 0; i < 4; ++i) {
          int row = m0 + mh + mf * 16 + q4 * 4 + i;
          ((float*)Cv)[(size_t)row * 1024 + col] = acc[mf][nf][i] + bv;
        }
    } else {
      if (col < 1024) {  // Q, pre-scaled for log2-domain softmax
#pragma unroll
        for (int mf = 0; mf < 4; ++mf)
#pragma unroll
          for (int i = 0; i < 4; ++i) {
            int row = m0 + mh + mf * 16 + q4 * 4 + i;
            ((_Float16*)Cv)[(size_t)row * 1024 + col] =
                (_Float16)((acc[mf][nf][i] + bv) * qscale);
          }
      } else if (col < 1088) {  // k_sum
        int ck = col - 1024;
#pragma unroll
        for (int mf = 0; mf < 4; ++mf)
#pragma unroll
          for (int i = 0; i < 4; ++i) {
            int row = m0 + mh + mf * 16 + q4 * 4 + i;
            kbo[(size_t)row * 64 + ck] = (_Float16)(acc[mf][nf][i] + bv);
          }
      } else {  // v_sum, transposed: vtb[(b*64+d)*S + s]
        int d = col - 1088;
#pragma unroll
        for (int mf = 0; mf < 4; ++mf) {
          int row0 = m0 + mh + mf * 16 + q4 * 4;
          int bb = row0 >> 11, sps = row0 & 2047;
          halfx4 o;
#pragma unroll
          for (int i = 0; i < 4; ++i) o[i] = (_Float16)(acc[mf][nf][i] + bv);
          *(halfx4*)&vto[((size_t)((bb << 6) + d)) * S_LEN + sps] = o;
        }
      }
    }
  }
}

// ---------------- flash v8: 8-wave blocks, wave-pair t-split ----------------
// Block = 4 s x 2 t-groups. Wave w: s = s0 + (w&3); group g = w>>2 computes
// sub-tile tq=g of each 128-t staging iter (halves the per-wave serial chain
// and the per-row LDS read fan-out). Partial (m,l,O) of the pair merge at the
// end through Ps scratch. Staging split 8 ways (2 gll16/wave). LDS 50 KB ->
// 3 blocks/CU = 24 waves/CU. Defer-rescale (THR=8, log2 domain) + setprio.
__global__ __launch_bounds__(512, 6) void flash_attn8(
    const _Float16* __restrict__ Qb, const _Float16* __restrict__ kb,
    const _Float16* __restrict__ vtb, _Float16* __restrict__ aob) {
  __shared__ _Float16 Ks[128][64];    // K tile [t][d], XOR-swizzled groups
  __shared__ _Float16 Vt[64][128];    // V^T tile [d][t], per-64-half swizzle
  __shared__ _Float16 Ps[8][16][72];  // per-wave P[h][t]; merge scratch at end
  int tid = threadIdx.x;
  int lane = tid & 63, w = tid >> 6, ln = lane & 15, q4 = lane >> 4;
  int g = w >> 2;                     // t-group (0: t 0..63, 1: t 64..127)
  int idx = 1023 - (int)blockIdx.x;   // longest chunks first
  int c = idx >> 1, b = idx & 1;
  int s0 = c * 4;
  int s = s0 + (w & 3);
  size_t bS = (size_t)b * S_LEN;

  const _Float16* qp = Qb + (bS + s) * DIM + ln * 64 + q4 * 8;
  halfx8 bq0 = *(const halfx8*)qp, bq1 = *(const halfx8*)(qp + 32);

  float m_run = -1e30f, l_run = 0.f;
  floatx4 oacc[4] = {};

  // K staging: wave w covers t-rows w*16..+15; lane: row += lane>>3, grp^row
  int rr = lane >> 3, ggk = ((lane & 7) ^ rr) * 8;
  const _Float16* kgp = kb + (bS + w * 16 + rr) * 64 + ggk;
  // V staging: wave w covers d-rows w*8..+7; lane: row += lane>>4,
  // t-col = half*64 + (vg ^ (row&7))*8, vg = lane&7, half = (lane>>3)&1
  int vr = lane >> 4;
  int vhalf = (lane >> 3) & 1, vg = lane & 7;
  const _Float16* vgp[2];
#pragma unroll
  for (int j = 0; j < 2; ++j) {
    int row = w * 8 + 4 * j + vr;
    vgp[j] = vtb + ((size_t)b * 64 + row) * S_LEN + vhalf * 64 +
             ((vg ^ (row & 7)) * 8);
  }
  int swk0 = (q4 ^ (ln & 7)) * 8;
  int swk1 = ((q4 + 4) ^ (ln & 7)) * 8;
  _Float16* Pw = &Ps[w][0][0];
  int nt = (s0 >> 7) + 1;

  for (int it = 0; it < nt; ++it) {
    int t0 = it << 7;
    __syncthreads();
#pragma unroll
    for (int j = 0; j < 2; ++j) {
      gll16(kgp + (size_t)(t0 + 8 * j) * 64, &Ks[w * 16 + 8 * j][0]);
      gll16(vgp[j] + t0, &Vt[w * 8 + 4 * j][0]);
    }
    __syncthreads();

    int t0q = t0 + (g << 6);
    if (t0q <= s) {  // wave-uniform
      // S^T = K Q^T (log2 domain): frag tf rows t = t0q + tf*16 + ln
      floatx4 sf[4];
      __builtin_amdgcn_s_setprio(1);
#pragma unroll
      for (int tf = 0; tf < 4; ++tf) {
        halfx8 ak0 = *(const halfx8*)&Ks[(g << 6) + tf * 16 + ln][swk0];
        halfx8 ak1 = *(const halfx8*)&Ks[(g << 6) + tf * 16 + ln][swk1];
        floatx4 z = {};
        z = mfma16(ak0, bq0, z);
        sf[tf] = mfma16(ak1, bq1, z);
      }
      __builtin_amdgcn_s_setprio(0);
      if (t0q + 63 > s) {  // causal mask on the boundary sub-tile only
#pragma unroll
        for (int tf = 0; tf < 4; ++tf)
#pragma unroll
          for (int i = 0; i < 4; ++i) {
            int t = t0q + tf * 16 + q4 * 4 + i;
            if (t > s) sf[tf][i] = -1e30f;
          }
      }
      float tm = fmaxf(fmaxf(sf[0][0], sf[0][1]), fmaxf(sf[0][2], sf[0][3]));
#pragma unroll
      for (int tf = 1; tf < 4; ++tf)
        tm = fmaxf(tm, fmaxf(fmaxf(sf[tf][0], sf[tf][1]),
                             fmaxf(sf[tf][2], sf[tf][3])));
      tm = fmaxf(tm, __shfl_xor(tm, 16));
      tm = fmaxf(tm, __shfl_xor(tm, 32));
      // defer-rescale (T13): skip O/l rescale while max drift <= 8 (log2)
      if (!__all(tm <= m_run + 8.f)) {
        float mn = fmaxf(m_run, tm);
        float alpha = exp2f(m_run - mn);
        m_run = mn;
        l_run *= alpha;
#pragma unroll
        for (int n2 = 0; n2 < 4; ++n2)
#pragma unroll
          for (int i = 0; i < 4; ++i) oacc[n2][i] *= alpha;
      }
      float rs = 0.f;
#pragma unroll
      for (int tf = 0; tf < 4; ++tf) {
        float p0 = exp2f(sf[tf][0] - m_run), p1 = exp2f(sf[tf][1] - m_run);
        float p2 = exp2f(sf[tf][2] - m_run), p3 = exp2f(sf[tf][3] - m_run);
        rs += (p0 + p1) + (p2 + p3);
        halfx4 pk;
        pk[0] = (_Float16)p0; pk[1] = (_Float16)p1;
        pk[2] = (_Float16)p2; pk[3] = (_Float16)p3;
        *(halfx4*)&Pw[ln * 72 + tf * 16 + q4 * 4] = pk;
      }
      rs += __shfl_xor(rs, 16);
      rs += __shfl_xor(rs, 32);
      l_run += rs;
      halfx8 bp0 = *(const halfx8*)&Pw[ln * 72 + q4 * 8];
      halfx8 bp1 = *(const halfx8*)&Pw[ln * 72 + 32 + q4 * 8];
      __builtin_amdgcn_s_setprio(1);
#pragma unroll
      for (int n2 = 0; n2 < 4; ++n2) {
        halfx8 av0 = *(const halfx8*)&Vt[n2 * 16 + ln][(g << 6) + swk0];
        halfx8 av1 = *(const halfx8*)&Vt[n2 * 16 + ln][(g << 6) + swk1];
        oacc[n2] = mfma16(av0, bp0, oacc[n2]);
        oacc[n2] = mfma16(av1, bp1, oacc[n2]);
      }
      __builtin_amdgcn_s_setprio(0);
    }
  }

  // ---- merge wave pair (w, w+4): g=1 publishes to Ps scratch, g=0 merges ---
  __syncthreads();  // everyone done with Ps / LDS
  if (g == 1) {
    float* sb = (float*)&Ps[(w & 3) * 2][0][0];  // 1152 floats per pair
#pragma unroll
    for (int n2 = 0; n2 < 4; ++n2)
#pragma unroll
      for (int i = 0; i < 4; ++i) sb[(n2 * 4 + i) * 64 + lane] = oacc[n2][i];
    sb[1024 + lane] = m_run;
    sb[1088 + lane] = l_run;
  }
  __syncthreads();
  if (g == 0) {
    float* sb = (float*)&Ps[w * 2][0][0];
    float m2 = sb[1024 + lane], l2 = sb[1088 + lane];
    float mn = fmaxf(m_run, m2);
    float a1 = exp2f(m_run - mn), a2 = exp2f(m2 - mn);
    float linv = 1.0f / (l_run * a1 + l2 * a2);
    // epilogue: O^T frag n2: h=ln, d=n2*16+q4*4+i
#pragma unroll
    for (int n2 = 0; n2 < 4; ++n2) {
      halfx4 o;
#pragma unroll
      for (int i = 0; i < 4; ++i)
        o[i] = (_Float16)((oacc[n2][i] * a1 + sb[(n2 * 4 + i) * 64 + lane] * a2) *
                          linv);
      *(halfx4*)(aob + (bS + s) * DIM + ln * 64 + n2 * 16 + q4 * 4) = o;
    }
  }
}

extern "C" void kernel_launch(void* const* d_in, const int* in_sizes, int n_in,
                              void* d_out, int out_size, void* d_ws,
                              size_t ws_size, hipStream_t stream) {
  const float* x    = (const float*)d_in[0];
  const float* wqkv = (const float*)d_in[1];
  const float* bqkv = (const float*)d_in[2];
  const float* wout = (const float*)d_in[3];
  const float* bout = (const float*)d_in[4];
  float* out = (float*)d_out;
  char* ws = (char*)d_ws;
  _Float16* xb    = (_Float16*)(ws);                               // 8 MB
  _Float16* qb    = (_Float16*)(ws + (8u << 20));                  // 8 MB
  _Float16* aob   = (_Float16*)(ws + (16u << 20));                 // 8 MB
  _Float16* kb    = (_Float16*)(ws + (24u << 20));                 // 512 KB
  _Float16* vtb   = (_Float16*)(ws + (24u << 20) + (512u << 10));  // 512 KB
  _Float16* wcomb = (_Float16*)(ws + (25u << 20));                 // 2.25 MB
  _Float16* woutb = (_Float16*)(ws + (27u << 20) + (512u << 10));  // 2 MB
  float*    bcomb = (float*)(ws + (29u << 20) + (512u << 10));     // 4.6 KB

  hipLaunchKernelGGL(prep_all, dim3(6656), dim3(256), 0, stream,
                     x, wqkv, bqkv, wout, xb, wcomb, woutb, bcomb);
  hipLaunchKernelGGL((gemm_t2<0>), dim3(32, 9), dim3(256), 0, stream,
                     xb, wcomb, bcomb, (void*)qb, kb, vtb);
  hipLaunchKernelGGL(flash_attn8, dim3(1024), dim3(512), 0, stream,
                     qb, kb, vtb, aob);
  hipLaunchKernelGGL((gemm_t2<1>), dim3(32, 8), dim3(256), 0, stream,
                     aob, woutb, bout, (void*)out, nullptr, nullptr);
}

// Round 2
// 166.349 us; speedup vs baseline: 1.0161x; 1.0009x over previous
//
#include <hip/hip_runtime.h>

// Problem: B=2, S=2048, D=1024, H=16, HD=64. fp32 in/out.
// Pipeline exploits head-summed K/V: k_sum = x @ (sum_h Wk_h)^T + sum_h bk_h.
//  1. prep_all:    x, Wout -> f16; wcomb = [Wq; Wred] f16 (1152x1024); bcomb
//  2. gemm_t2<0>:  [Q*scale | k_sum | v_sum^T] = x @ wcomb^T + bcomb (N=1152)
//  3. flash_attn9: 8-wave blocks, wave-pair t-split; each block runs TWO
//                  chunks (p, 511-p) -> exactly 17 staging-units per block,
//                  grid 512 = 2 blk/CU, perfectly balanced (no LPT tail)
//  4. gemm_t2<1>:  out = ao @ Wout^T + bout   (4096x1024x1024) -> f32

#define S_LEN 2048
#define DIM 1024

using floatx4 = __attribute__((ext_vector_type(4))) float;
using halfx8  = __attribute__((ext_vector_type(8))) _Float16;
using halfx4  = __attribute__((ext_vector_type(4))) _Float16;

__device__ __forceinline__ floatx4 mfma16(halfx8 a, halfx8 b, floatx4 c) {
  return __builtin_amdgcn_mfma_f32_16x16x32_f16(a, b, c, 0, 0, 0);
}

// async global->LDS, 16B per lane; lds dst is wave-uniform base + lane*16
__device__ __forceinline__ void gll16(const void* g, void* l) {
  __builtin_amdgcn_global_load_lds(
      (const __attribute__((address_space(1))) void*)g,
      (__attribute__((address_space(3))) void*)l, 16, 0, 0);
}

// ---------------- prep: conversions + combined weights ----------------
__global__ __launch_bounds__(256) void prep_all(
    const float* __restrict__ x, const float* __restrict__ wqkv,
    const float* __restrict__ bqkv, const float* __restrict__ wout,
    _Float16* __restrict__ xb, _Float16* __restrict__ wcomb,
    _Float16* __restrict__ woutb, float* __restrict__ bcomb) {
  int bx = blockIdx.x;
  if (bx < 6144) {
    size_t i4 = ((size_t)bx * 256 + threadIdx.x) * 4;
    const float* src;
    _Float16* dst;
    size_t off;
    if (i4 < 4194304) { src = x; dst = xb; off = i4; }
    else if (i4 < 5242880) { src = wqkv; dst = wcomb; off = i4 - 4194304; }
    else { src = wout; dst = woutb; off = i4 - 5242880; }
    float4 v = *(const float4*)(src + off);
    halfx4 o;
    o[0] = (_Float16)v.x; o[1] = (_Float16)v.y;
    o[2] = (_Float16)v.z; o[3] = (_Float16)v.w;
    *(halfx4*)(dst + off) = o;
  } else {
    int gid = (bx - 6144) * 256 + threadIdx.x;  // 131072 threads
    int c = gid >> 10, j = gid & 1023;
    int row0 = (c < 64) ? (1024 + c) : (2048 + c - 64);
    float s = 0.f;
#pragma unroll
    for (int h = 0; h < 16; ++h) s += wqkv[(size_t)(row0 + h * 64) * 1024 + j];
    wcomb[(size_t)1024 * 1024 + gid] = (_Float16)s;
    if (gid < 1024) bcomb[gid] = bqkv[gid];
    if (gid < 128) {
      int b0 = (gid < 64) ? (1024 + gid) : (2048 + gid - 64);
      float sb = 0.f;
#pragma unroll
      for (int h = 0; h < 16; ++h) sb += bqkv[b0 + h * 64];
      bcomb[1024 + gid] = sb;
    }
  }
}

// ------- gemm_t2: 128M x 128N tile (m97-style), BK=64, 2 barriers/step -----
// Wave w -> 64x64 quadrant: rows (w&1)*64, cols (w>>1)*64; 4x4 16x16 frags.
// gll16 staging with XOR col-group swizzle (row r group g at g^(r&7)).
// MODE 0: N=1152 fused epilogue -> qb (*scale), kb, vtb(V^T). MODE 1: f32 out.
template <int MODE>
__global__ __launch_bounds__(256, 2) void gemm_t2(
    const _Float16* __restrict__ A, const _Float16* __restrict__ W,
    const float* __restrict__ bias, void* __restrict__ Cv,
    _Float16* __restrict__ kbo, _Float16* __restrict__ vto) {
  const int K = 1024;
  __shared__ _Float16 As[128][64];  // 16 KB
  __shared__ _Float16 Ws[128][64];  // 16 KB
  int tid = threadIdx.x;
  int lane = tid & 63, w = tid >> 6, ln = lane & 15, q4 = lane >> 4;
  int m0 = blockIdx.x * 128, n0 = blockIdx.y * 128;
  int mh = (w & 1) * 64, nh = (w >> 1) * 64;
  int rr = lane >> 3, gg = ((lane & 7) ^ rr) * 8;  // staging lane row/col
  const _Float16* agp = A + (size_t)(m0 + w * 32 + rr) * K + gg;
  const _Float16* wgp = W + (size_t)(n0 + w * 32 + rr) * K + gg;
  floatx4 acc[4][4] = {};
  for (int kt = 0; kt < K; kt += 64) {
    __syncthreads();  // readers done with previous tile
#pragma unroll
    for (int j = 0; j < 4; ++j) {
      gll16(agp + (size_t)(8 * j) * K + kt, &As[w * 32 + 8 * j][0]);
      gll16(wgp + (size_t)(8 * j) * K + kt, &Ws[w * 32 + 8 * j][0]);
    }
    __syncthreads();  // staging visible
#pragma unroll
    for (int kh = 0; kh < 2; ++kh) {
      int sw = ((q4 + 4 * kh) ^ (ln & 7)) * 8;
      halfx8 bf[4];
#pragma unroll
      for (int nf = 0; nf < 4; ++nf)
        bf[nf] = *(const halfx8*)&Ws[nh + nf * 16 + ln][sw];
#pragma unroll
      for (int mf = 0; mf < 4; ++mf) {
        halfx8 af = *(const halfx8*)&As[mh + mf * 16 + ln][sw];
#pragma unroll
        for (int nf = 0; nf < 4; ++nf)
          acc[mf][nf] = mfma16(af, bf[nf], acc[mf][nf]);
      }
    }
  }
  const float qscale = 0.18033688011112042f;  // (1/sqrt(64)) * log2(e)
#pragma unroll
  for (int nf = 0; nf < 4; ++nf) {
    int col = n0 + nh + nf * 16 + ln;
    float bv = bias[col];
    if constexpr (MODE == 1) {
#pragma unroll
      for (int mf = 0; mf < 4; ++mf)
#pragma unroll
        for (int i = 0; i < 4; ++i) {
          int row = m0 + mh + mf * 16 + q4 * 4 + i;
          ((float*)Cv)[(size_t)row * 1024 + col] = acc[mf][nf][i] + bv;
        }
    } else {
      if (col < 1024) {  // Q, pre-scaled for log2-domain softmax
#pragma unroll
        for (int mf = 0; mf < 4; ++mf)
#pragma unroll
          for (int i = 0; i < 4; ++i) {
            int row = m0 + mh + mf * 16 + q4 * 4 + i;
            ((_Float16*)Cv)[(size_t)row * 1024 + col] =
                (_Float16)((acc[mf][nf][i] + bv) * qscale);
          }
      } else if (col < 1088) {  // k_sum
        int ck = col - 1024;
#pragma unroll
        for (int mf = 0; mf < 4; ++mf)
#pragma unroll
          for (int i = 0; i < 4; ++i) {
            int row = m0 + mh + mf * 16 + q4 * 4 + i;
            kbo[(size_t)row * 64 + ck] = (_Float16)(acc[mf][nf][i] + bv);
          }
      } else {  // v_sum, transposed: vtb[(b*64+d)*S + s]
        int d = col - 1088;
#pragma unroll
        for (int mf = 0; mf < 4; ++mf) {
          int row0 = m0 + mh + mf * 16 + q4 * 4;
          int bb = row0 >> 11, sps = row0 & 2047;
          halfx4 o;
#pragma unroll
          for (int i = 0; i < 4; ++i) o[i] = (_Float16)(acc[mf][nf][i] + bv);
          *(halfx4*)&vto[((size_t)((bb << 6) + d)) * S_LEN + sps] = o;
        }
      }
    }
  }
}

// ---------------- flash v9: paired chunks, uniform 17 units/block ----------
// Block = 4 s x 2 t-groups (8 waves). Wave w: s = s0 + (w&3); group g = w>>2
// computes sub-tile tq=g of each 128-t staging iter. Each block processes
// chunks c = p and c = 511-p sequentially: nt(p)+nt(511-p) == 17 for all p,
// so all 512 blocks carry identical work -> no imbalance, no schedule tail.
// 2 blocks/CU (LDS 50K), defer-rescale (THR=8, log2 domain), setprio.
__global__ __launch_bounds__(512, 4) void flash_attn9(
    const _Float16* __restrict__ Qb, const _Float16* __restrict__ kb,
    const _Float16* __restrict__ vtb, _Float16* __restrict__ aob) {
  __shared__ _Float16 Ks[128][64];    // K tile [t][d], XOR-swizzled groups
  __shared__ _Float16 Vt[64][128];    // V^T tile [d][t], per-64-half swizzle
  __shared__ _Float16 Ps[8][16][72];  // per-wave P[h][t]; merge scratch at end
  int tid = threadIdx.x;
  int lane = tid & 63, w = tid >> 6, ln = lane & 15, q4 = lane >> 4;
  int g = w >> 2;                     // t-group (0: t 0..63, 1: t 64..127)
  int bx = (int)blockIdx.x;
  int p = bx >> 1, b = bx & 1;
  size_t bS = (size_t)b * S_LEN;

  // K staging: wave w covers t-rows w*16..+15; lane: row += lane>>3, grp^row
  int rr = lane >> 3, ggk = ((lane & 7) ^ rr) * 8;
  const _Float16* kgp = kb + (bS + w * 16 + rr) * 64 + ggk;
  // V staging: wave w covers d-rows w*8..+7; lane: row += lane>>4,
  // t-col = half*64 + (vg ^ (row&7))*8, vg = lane&7, half = (lane>>3)&1
  int vr = lane >> 4;
  int vhalf = (lane >> 3) & 1, vg = lane & 7;
  const _Float16* vgp[2];
#pragma unroll
  for (int j = 0; j < 2; ++j) {
    int row = w * 8 + 4 * j + vr;
    vgp[j] = vtb + ((size_t)b * 64 + row) * S_LEN + vhalf * 64 +
             ((vg ^ (row & 7)) * 8);
  }
  int swk0 = (q4 ^ (ln & 7)) * 8;
  int swk1 = ((q4 + 4) ^ (ln & 7)) * 8;
  _Float16* Pw = &Ps[w][0][0];

  for (int pass = 0; pass < 2; ++pass) {
    int c = pass ? (511 - p) : p;
    int s0 = c * 4;
    int s = s0 + (w & 3);

    const _Float16* qp = Qb + (bS + s) * DIM + ln * 64 + q4 * 8;
    halfx8 bq0 = *(const halfx8*)qp, bq1 = *(const halfx8*)(qp + 32);

    float m_run = -1e30f, l_run = 0.f;
    floatx4 oacc[4] = {};
    int nt = (s0 >> 7) + 1;

    for (int it = 0; it < nt; ++it) {
      int t0 = it << 7;
      __syncthreads();
#pragma unroll
      for (int j = 0; j < 2; ++j) {
        gll16(kgp + (size_t)(t0 + 8 * j) * 64, &Ks[w * 16 + 8 * j][0]);
        gll16(vgp[j] + t0, &Vt[w * 8 + 4 * j][0]);
      }
      __syncthreads();

      int t0q = t0 + (g << 6);
      if (t0q <= s) {  // wave-uniform
        // S^T = K Q^T (log2 domain): frag tf rows t = t0q + tf*16 + ln
        floatx4 sf[4];
        __builtin_amdgcn_s_setprio(1);
#pragma unroll
        for (int tf = 0; tf < 4; ++tf) {
          halfx8 ak0 = *(const halfx8*)&Ks[(g << 6) + tf * 16 + ln][swk0];
          halfx8 ak1 = *(const halfx8*)&Ks[(g << 6) + tf * 16 + ln][swk1];
          floatx4 z = {};
          z = mfma16(ak0, bq0, z);
          sf[tf] = mfma16(ak1, bq1, z);
        }
        __builtin_amdgcn_s_setprio(0);
        if (t0q + 63 > s) {  // causal mask on the boundary sub-tile only
#pragma unroll
          for (int tf = 0; tf < 4; ++tf)
#pragma unroll
            for (int i = 0; i < 4; ++i) {
              int t = t0q + tf * 16 + q4 * 4 + i;
              if (t > s) sf[tf][i] = -1e30f;
            }
        }
        float tm = fmaxf(fmaxf(sf[0][0], sf[0][1]), fmaxf(sf[0][2], sf[0][3]));
#pragma unroll
        for (int tf = 1; tf < 4; ++tf)
          tm = fmaxf(tm, fmaxf(fmaxf(sf[tf][0], sf[tf][1]),
                               fmaxf(sf[tf][2], sf[tf][3])));
        tm = fmaxf(tm, __shfl_xor(tm, 16));
        tm = fmaxf(tm, __shfl_xor(tm, 32));
        // defer-rescale (T13): skip O/l rescale while max drift <= 8 (log2)
        if (!__all(tm <= m_run + 8.f)) {
          float mn = fmaxf(m_run, tm);
          float alpha = exp2f(m_run - mn);
          m_run = mn;
          l_run *= alpha;
#pragma unroll
          for (int n2 = 0; n2 < 4; ++n2)
#pragma unroll
            for (int i = 0; i < 4; ++i) oacc[n2][i] *= alpha;
        }
        float rs = 0.f;
#pragma unroll
        for (int tf = 0; tf < 4; ++tf) {
          float p0 = exp2f(sf[tf][0] - m_run), p1 = exp2f(sf[tf][1] - m_run);
          float p2 = exp2f(sf[tf][2] - m_run), p3 = exp2f(sf[tf][3] - m_run);
          rs += (p0 + p1) + (p2 + p3);
          halfx4 pk;
          pk[0] = (_Float16)p0; pk[1] = (_Float16)p1;
          pk[2] = (_Float16)p2; pk[3] = (_Float16)p3;
          *(halfx4*)&Pw[ln * 72 + tf * 16 + q4 * 4] = pk;
        }
        rs += __shfl_xor(rs, 16);
        rs += __shfl_xor(rs, 32);
        l_run += rs;
        halfx8 bp0 = *(const halfx8*)&Pw[ln * 72 + q4 * 8];
        halfx8 bp1 = *(const halfx8*)&Pw[ln * 72 + 32 + q4 * 8];
        __builtin_amdgcn_s_setprio(1);
#pragma unroll
        for (int n2 = 0; n2 < 4; ++n2) {
          halfx8 av0 = *(const halfx8*)&Vt[n2 * 16 + ln][(g << 6) + swk0];
          halfx8 av1 = *(const halfx8*)&Vt[n2 * 16 + ln][(g << 6) + swk1];
          oacc[n2] = mfma16(av0, bp0, oacc[n2]);
          oacc[n2] = mfma16(av1, bp1, oacc[n2]);
        }
        __builtin_amdgcn_s_setprio(0);
      }
    }

    // -- merge wave pair (w, w+4): g=1 publishes to Ps scratch, g=0 merges --
    __syncthreads();  // everyone done with Ps / LDS
    if (g == 1) {
      float* sb = (float*)&Ps[(w & 3) * 2][0][0];  // 1152 floats per pair
#pragma unroll
      for (int n2 = 0; n2 < 4; ++n2)
#pragma unroll
        for (int i = 0; i < 4; ++i) sb[(n2 * 4 + i) * 64 + lane] = oacc[n2][i];
      sb[1024 + lane] = m_run;
      sb[1088 + lane] = l_run;
    }
    __syncthreads();
    if (g == 0) {
      float* sb = (float*)&Ps[w * 2][0][0];
      float m2 = sb[1024 + lane], l2 = sb[1088 + lane];
      float mn = fmaxf(m_run, m2);
      float a1 = exp2f(m_run - mn), a2 = exp2f(m2 - mn);
      float linv = 1.0f / (l_run * a1 + l2 * a2);
      // epilogue: O^T frag n2: h=ln, d=n2*16+q4*4+i
#pragma unroll
      for (int n2 = 0; n2 < 4; ++n2) {
        halfx4 o;
#pragma unroll
        for (int i = 0; i < 4; ++i)
          o[i] = (_Float16)(
              (oacc[n2][i] * a1 + sb[(n2 * 4 + i) * 64 + lane] * a2) * linv);
        *(halfx4*)(aob + (bS + s) * DIM + ln * 64 + n2 * 16 + q4 * 4) = o;
      }
    }
  }
}

extern "C" void kernel_launch(void* const* d_in, const int* in_sizes, int n_in,
                              void* d_out, int out_size, void* d_ws,
                              size_t ws_size, hipStream_t stream) {
  const float* x    = (const float*)d_in[0];
  const float* wqkv = (const float*)d_in[1];
  const float* bqkv = (const float*)d_in[2];
  const float* wout = (const float*)d_in[3];
  const float* bout = (const float*)d_in[4];
  float* out = (float*)d_out;
  char* ws = (char*)d_ws;
  _Float16* xb    = (_Float16*)(ws);                               // 8 MB
  _Float16* qb    = (_Float16*)(ws + (8u << 20));                  // 8 MB
  _Float16* aob   = (_Float16*)(ws + (16u << 20));                 // 8 MB
  _Float16* kb    = (_Float16*)(ws + (24u << 20));                 // 512 KB
  _Float16* vtb   = (_Float16*)(ws + (24u << 20) + (512u << 10));  // 512 KB
  _Float16* wcomb = (_Float16*)(ws + (25u << 20));                 // 2.25 MB
  _Float16* woutb = (_Float16*)(ws + (27u << 20) + (512u << 10));  // 2 MB
  float*    bcomb = (float*)(ws + (29u << 20) + (512u << 10));     // 4.6 KB

  hipLaunchKernelGGL(prep_all, dim3(6656), dim3(256), 0, stream,
                     x, wqkv, bqkv, wout, xb, wcomb, woutb, bcomb);
  hipLaunchKernelGGL((gemm_t2<0>), dim3(32, 9), dim3(256), 0, stream,
                     xb, wcomb, bcomb, (void*)qb, kb, vtb);
  hipLaunchKernelGGL(flash_attn9, dim3(512), dim3(512), 0, stream,
                     qb, kb, vtb, aob);
  hipLaunchKernelGGL((gemm_t2<1>), dim3(32, 8), dim3(256), 0, stream,
                     aob, woutb, bout, (void*)out, nullptr, nullptr);
}